// Round 11
// baseline (33.269 us; speedup 1.0000x reference)
//
#include <hip/hip_runtime.h>

// Grouped conv1d over W + roll(+1) along H, bf16 MFMA 16x16x32.
// x: (128, 48, 28, 28) f32, channel = g*24+ci
// w: (24, 96, 7) f32, w[ci][o][k], shared across the 2 groups
// out: (128, 192, 28, 28) f32, channel = g*96+o
//
// R11 = R10 + two LDS fixes (theory: LDS pipe is the binder at ~28us):
//  (1) xs row stride 24 -> 26 shorts (13 dwords, coprime 32): staging
//      ds_write was an 8-way bank conflict (stride 12 dwords, gcd 4);
//      now conflict-free on both write and A-read.
//  (2) nt-pairing: 6 waves = (np 0..2) x (mh 0..1); each wave holds B for
//      2 N-tiles (48 VGPR) and covers half the M-tiles -> A ds_read traffic
//      halves (258KB -> 126KB per block-tile).
//
// GEMM per tile: M=112 (4 output rows x 28 W), N=96, K=168 pad 192.
// k-permutation (A and B must match): q = ks*4+kgrp (0..23);
//   q<21: k=q/3, ci=(q%3)*8+j ; q>=21: zero (B side).
// Block owns OUTPUT rows 4ht..4ht+3; src rows (4ht+hl-1) mod 28 absorb roll.

typedef __attribute__((ext_vector_type(8))) short short8;
typedef __attribute__((ext_vector_type(4))) float float4v;

#define B_     128
#define H_     28
#define W_     28
#define CIN_   24
#define COUT_  96
#define K_     7
#define KSTEPS 6
#define NT_    6
#define HW_    784
#define XROW   26      // padded shorts per (hl,p) row: 24 data + 2 pad

// float -> bf16 bits, RNE (cold path: wfrag kernel only)
static __device__ __forceinline__ short f2bf(float f) {
    union { float f; unsigned u; } v; v.f = f;
    return (short)((v.u + 0x7fffu + ((v.u >> 16) & 1u)) >> 16);
}

// packed 2x f32 -> bf16x2 in one instruction (lo <- a, hi <- b)
static __device__ __forceinline__ unsigned cvt_pk_bf16(float a, float b) {
    unsigned r;
    asm("v_cvt_pk_bf16_f32 %0, %1, %2" : "=v"(r) : "v"(a), "v"(b));
    return r;
}

// Pre-pack weights into B-fragment order with the permuted k-axis.
// B-frag (16x16x32): lane l holds B[hw=(l>>4)*8+j][col=l&15], j=0..7
__global__ __launch_bounds__(64)
void wfrag_kernel(const float* __restrict__ w, short8* __restrict__ wf) {
    const int idx  = blockIdx.x;          // 0..35 = ks*6 + nt
    const int ks   = idx / 6, nt = idx - ks * 6;
    const int lane = threadIdx.x;
    const int c    = nt * 16 + (lane & 15);
    const int q    = ks * 4 + (lane >> 4);
    short8 v;
    if (q < 21) {
        const int k   = (q * 11) >> 5;    // q/3 for q in 0..23
        const int ci0 = (q - 3 * k) * 8;
#pragma unroll
        for (int j = 0; j < 8; ++j)
            v[j] = f2bf(w[(ci0 + j) * (COUT_ * K_) + c * K_ + k]);
    } else {
#pragma unroll
        for (int j = 0; j < 8; ++j) v[j] = 0;   // zero-pad K (A garbage harmless)
    }
    wf[idx * 64 + lane] = v;
}

__global__ __launch_bounds__(384, 4)
void conv_mfma_kernel(const float* __restrict__ x,
                      const short8* __restrict__ wfg,
                      float* __restrict__ out) {
    const int bid = blockIdx.x;           // (b*2+g)*7 + ht
    const int ht  = bid % 7;
    const int bg  = bid / 7;
    const int g   = bg & 1;
    const int b   = bg >> 1;
    const int tid  = threadIdx.x;
    const int lane = tid & 63;
    const int wv   = tid >> 6;            // 0..5
    const int np   = wv >> 1;             // N-pair 0..2: nt {2np, 2np+1}
    const int mh   = wv & 1;              // M-half: 0 -> mt 0..3, 1 -> mt 4..6
    const int cgrp = lane & 15;
    const int kgrp = lane >> 4;

    // xs[hl][p][ci] bf16 with padded row stride XROW=26. 7488 B.
    __shared__ __align__(16) short xs[4 * 36 * XROW];

    // ---- x staging: issue all global dwords first (maximum MLP)
    float v0r[5], v1r[5];
#pragma unroll
    for (int it = 0; it < 5; ++it) {
        const int idx = tid + it * 384;
        if (idx < 1728) {
            const int p  = idx % 36;
            const int r  = idx / 36;
            const int cp = r % 12;
            const int hl = r / 12;
            const int ws = p - 3;
            const int rsrc = (4 * ht + hl + 27) % 28;   // (output row - 1) mod 28
            float a0 = 0.0f, a1 = 0.0f;
            if (ws >= 0 && ws < W_) {
                const size_t base =
                    ((size_t)(b * 48 + g * CIN_ + cp * 2) * H_ + rsrc) * W_ + ws;
                a0 = x[base];
                a1 = x[base + (size_t)HW_];
            }
            v0r[it] = a0; v1r[it] = a1;
        }
    }

    // ---- B fragments for TWO N-tiles: 12 L2-hot dwordx4 -> 48 VGPR
    short8 br0[KSTEPS], br1[KSTEPS];
#pragma unroll
    for (int ks = 0; ks < KSTEPS; ++ks) {
        br0[ks] = wfg[(ks * NT_ + 2 * np)     * 64 + lane];
        br1[ks] = wfg[(ks * NT_ + 2 * np + 1) * 64 + lane];
    }

    // ---- convert + LDS write: dword addr = (hl*36+p)*13 + cp; lanes have p
    // fastest -> stride 13 dwords, coprime 32 -> conflict-free.
#pragma unroll
    for (int it = 0; it < 5; ++it) {
        const int idx = tid + it * 384;
        if (idx < 1728) {
            const int p  = idx % 36;
            const int r  = idx / 36;
            const int cp = r % 12;
            const int hl = r / 12;
            ((unsigned*)xs)[(hl * 36 + p) * 13 + cp] = cvt_pk_bf16(v0r[it], v1r[it]);
        }
    }
    __syncthreads();

    // Per-lane k-step LDS offsets (A side of the shared k permutation)
    int koff[KSTEPS];
#pragma unroll
    for (int ks = 0; ks < KSTEPS; ++ks) {
        const int q   = ks * 4 + kgrp;
        const int k   = (q * 11) >> 5;
        const int ci0 = (q - 3 * k) * 8;
        koff[ks] = k * XROW + ci0;        // shorts; 16B-aligned (ci0 even*8)
    }

    const int c_out0 = (2 * np)     * 16 + cgrp;
    const int c_out1 = (2 * np + 1) * 16 + cgrp;
    float* cb0 = out + ((size_t)(b * 192 + g * COUT_ + c_out0)) * HW_;
    float* cb1 = out + ((size_t)(b * 192 + g * COUT_ + c_out1)) * HW_;

    const int mt0 = mh * 4;               // mh=0: mt 0..3, mh=1: mt 4..6
    const int mtn = mh ? 3 : 4;

#pragma unroll
    for (int mti = 0; mti < 4; ++mti) {
        if (mti < mtn) {
            const int mt = mt0 + mti;
            const int mA = mt * 16 + cgrp;
            const int hA = mA / 28;
            const int tA = mA - hA * 28;
            const int abase = (hA * 36 + tA) * XROW;
            float4v a0 = (float4v)(0.0f);
            float4v a1 = (float4v)(0.0f);
#pragma unroll
            for (int ks = 0; ks < KSTEPS; ++ks) {
                const short8 a = *(const short8*)&xs[abase + koff[ks]];
                a0 = __builtin_amdgcn_mfma_f32_16x16x32_bf16(a, br0[ks], a0, 0, 0, 0);
                a1 = __builtin_amdgcn_mfma_f32_16x16x32_bf16(a, br1[ks], a1, 0, 0, 0);
            }
            // D-quad j=0..3 = 4 consecutive t in one h-row (m0 % 4 == 0, 4|28)
            const int m0 = mt * 16 + kgrp * 4;
            const int hl = m0 / 28;
            const int t0 = m0 - hl * 28;
            const int hd = 4 * ht + hl;   // output row (roll absorbed in rsrc)
            float4 u0; u0.x = a0[0]; u0.y = a0[1]; u0.z = a0[2]; u0.w = a0[3];
            float4 u1; u1.x = a1[0]; u1.y = a1[1]; u1.z = a1[2]; u1.w = a1[3];
            *(float4*)&cb0[hd * W_ + t0] = u0;
            *(float4*)&cb1[hd * W_ + t0] = u1;
        }
    }
}

extern "C" void kernel_launch(void* const* d_in, const int* in_sizes, int n_in,
                              void* d_out, int out_size, void* d_ws, size_t ws_size,
                              hipStream_t stream) {
    const float* x = (const float*)d_in[0];
    const float* w = (const float*)d_in[1];
    float* out = (float*)d_out;
    short8* wf = (short8*)d_ws;           // 36*64*16B = 36864 B

    wfrag_kernel<<<36, 64, 0, stream>>>(w, wf);
    conv_mfma_kernel<<<B_ * 2 * 7, 384, 0, stream>>>(x, wf, out);
}

// Round 12
// 31.913 us; speedup vs baseline: 1.0425x; 1.0425x over previous
//
#include <hip/hip_runtime.h>

// Grouped conv1d over W + roll(+1) along H, bf16 MFMA 16x16x32.
// x: (128, 48, 28, 28) f32, channel = g*24+ci
// w: (24, 96, 7) f32, w[ci][o][k], shared across the 2 groups
// out: (128, 192, 28, 28) f32, channel = g*96+o
//
// R12 = R10 + nt-pairing ONLY (R11 retried with the alignment bug fixed:
// XROW stays 24 shorts = 48B rows so short8 A-reads stay 16B-aligned).
// Each wave holds B for 2 N-tiles (48 VGPR) and covers half the M-tiles:
//  - A ds_read_b128 traffic halves (each read feeds 2 MFMAs)
//  - inner loop = 2 independent acc chains (R10 had one serial 6-MFMA chain)
//
// GEMM per tile: M=112 (4 output rows x 28 W), N=96, K=168 pad 192.
// k-permutation (A and B must match): q = ks*4+kgrp (0..23);
//   q<21: k=q/3, ci=(q%3)*8+j ; q>=21: zero (B side).
// Block owns OUTPUT rows 4ht..4ht+3; src rows (4ht+hl-1) mod 28 absorb roll.

typedef __attribute__((ext_vector_type(8))) short short8;
typedef __attribute__((ext_vector_type(4))) float float4v;

#define B_     128
#define H_     28
#define W_     28
#define CIN_   24
#define COUT_  96
#define K_     7
#define KSTEPS 6
#define NT_    6
#define HW_    784

// float -> bf16 bits, RNE (cold path: wfrag kernel only)
static __device__ __forceinline__ short f2bf(float f) {
    union { float f; unsigned u; } v; v.f = f;
    return (short)((v.u + 0x7fffu + ((v.u >> 16) & 1u)) >> 16);
}

// packed 2x f32 -> bf16x2 in one instruction (lo <- a, hi <- b)
static __device__ __forceinline__ unsigned cvt_pk_bf16(float a, float b) {
    unsigned r;
    asm("v_cvt_pk_bf16_f32 %0, %1, %2" : "=v"(r) : "v"(a), "v"(b));
    return r;
}

// Pre-pack weights into B-fragment order with the permuted k-axis.
// B-frag (16x16x32): lane l holds B[hw=(l>>4)*8+j][col=l&15], j=0..7
__global__ __launch_bounds__(64)
void wfrag_kernel(const float* __restrict__ w, short8* __restrict__ wf) {
    const int idx  = blockIdx.x;          // 0..35 = ks*6 + nt
    const int ks   = idx / 6, nt = idx - ks * 6;
    const int lane = threadIdx.x;
    const int c    = nt * 16 + (lane & 15);
    const int q    = ks * 4 + (lane >> 4);
    short8 v;
    if (q < 21) {
        const int k   = (q * 11) >> 5;    // q/3 for q in 0..23
        const int ci0 = (q - 3 * k) * 8;
#pragma unroll
        for (int j = 0; j < 8; ++j)
            v[j] = f2bf(w[(ci0 + j) * (COUT_ * K_) + c * K_ + k]);
    } else {
#pragma unroll
        for (int j = 0; j < 8; ++j) v[j] = 0;   // zero-pad K (A garbage harmless)
    }
    wf[idx * 64 + lane] = v;
}

__global__ __launch_bounds__(384, 4)
void conv_mfma_kernel(const float* __restrict__ x,
                      const short8* __restrict__ wfg,
                      float* __restrict__ out) {
    const int bid = blockIdx.x;           // (b*2+g)*7 + ht
    const int ht  = bid % 7;
    const int bg  = bid / 7;
    const int g   = bg & 1;
    const int b   = bg >> 1;
    const int tid  = threadIdx.x;
    const int lane = tid & 63;
    const int wv   = tid >> 6;            // 0..5
    const int np   = wv >> 1;             // N-pair 0..2: nt {2np, 2np+1}
    const int mh   = wv & 1;              // M-half: 0 -> mt 0..3, 1 -> mt 4..6
    const int cgrp = lane & 15;
    const int kgrp = lane >> 4;

    // xs[hl][p][ci] bf16, rows = 24 shorts = 48B (16B-aligned reads). 6912 B.
    __shared__ __align__(16) short xs[4 * 36 * 24];

    // ---- x staging: issue all global dwords first (maximum MLP)
    float v0r[5], v1r[5];
#pragma unroll
    for (int it = 0; it < 5; ++it) {
        const int idx = tid + it * 384;
        if (idx < 1728) {
            const int p  = idx % 36;
            const int r  = idx / 36;
            const int cp = r % 12;
            const int hl = r / 12;
            const int ws = p - 3;
            const int rsrc = (4 * ht + hl + 27) % 28;   // (output row - 1) mod 28
            float a0 = 0.0f, a1 = 0.0f;
            if (ws >= 0 && ws < W_) {
                const size_t base =
                    ((size_t)(b * 48 + g * CIN_ + cp * 2) * H_ + rsrc) * W_ + ws;
                a0 = x[base];
                a1 = x[base + (size_t)HW_];
            }
            v0r[it] = a0; v1r[it] = a1;
        }
    }

    // ---- B fragments for TWO N-tiles: 12 L2-hot dwordx4 -> 48 VGPR
    short8 br0[KSTEPS], br1[KSTEPS];
#pragma unroll
    for (int ks = 0; ks < KSTEPS; ++ks) {
        br0[ks] = wfg[(ks * NT_ + 2 * np)     * 64 + lane];
        br1[ks] = wfg[(ks * NT_ + 2 * np + 1) * 64 + lane];
    }

    // ---- convert + LDS write (single v_cvt_pk_bf16_f32 per dword)
#pragma unroll
    for (int it = 0; it < 5; ++it) {
        const int idx = tid + it * 384;
        if (idx < 1728) {
            const int p  = idx % 36;
            const int r  = idx / 36;
            const int cp = r % 12;
            const int hl = r / 12;
            ((unsigned*)xs)[(hl * 36 + p) * 12 + cp] = cvt_pk_bf16(v0r[it], v1r[it]);
        }
    }
    __syncthreads();

    // Per-lane k-step LDS offsets (A side of the shared k permutation)
    int koff[KSTEPS];
#pragma unroll
    for (int ks = 0; ks < KSTEPS; ++ks) {
        const int q   = ks * 4 + kgrp;
        const int k   = (q * 11) >> 5;
        const int ci0 = (q - 3 * k) * 8;
        koff[ks] = k * 24 + ci0;          // shorts; byte = k*48 + {0,16,32}
    }

    const int c_out0 = (2 * np)     * 16 + cgrp;
    const int c_out1 = (2 * np + 1) * 16 + cgrp;
    float* cb0 = out + ((size_t)(b * 192 + g * COUT_ + c_out0)) * HW_;
    float* cb1 = out + ((size_t)(b * 192 + g * COUT_ + c_out1)) * HW_;

    const int mt0 = mh * 4;               // mh=0: mt 0..3, mh=1: mt 4..6
    const int mtn = mh ? 3 : 4;

#pragma unroll
    for (int mti = 0; mti < 4; ++mti) {
        if (mti < mtn) {
            const int mt = mt0 + mti;
            const int mA = mt * 16 + cgrp;
            const int hA = mA / 28;
            const int tA = mA - hA * 28;
            const int abase = (hA * 36 + tA) * 24;
            float4v a0 = (float4v)(0.0f);
            float4v a1 = (float4v)(0.0f);
#pragma unroll
            for (int ks = 0; ks < KSTEPS; ++ks) {
                const short8 a = *(const short8*)&xs[abase + koff[ks]];
                a0 = __builtin_amdgcn_mfma_f32_16x16x32_bf16(a, br0[ks], a0, 0, 0, 0);
                a1 = __builtin_amdgcn_mfma_f32_16x16x32_bf16(a, br1[ks], a1, 0, 0, 0);
            }
            // D-quad j=0..3 = 4 consecutive t in one h-row (m0 % 4 == 0, 4|28)
            const int m0 = mt * 16 + kgrp * 4;
            const int hl = m0 / 28;
            const int t0 = m0 - hl * 28;
            const int hd = 4 * ht + hl;   // output row (roll absorbed in rsrc)
            float4 u0; u0.x = a0[0]; u0.y = a0[1]; u0.z = a0[2]; u0.w = a0[3];
            float4 u1; u1.x = a1[0]; u1.y = a1[1]; u1.z = a1[2]; u1.w = a1[3];
            *(float4*)&cb0[hd * W_ + t0] = u0;
            *(float4*)&cb1[hd * W_ + t0] = u1;
        }
    }
}

extern "C" void kernel_launch(void* const* d_in, const int* in_sizes, int n_in,
                              void* d_out, int out_size, void* d_ws, size_t ws_size,
                              hipStream_t stream) {
    const float* x = (const float*)d_in[0];
    const float* w = (const float*)d_in[1];
    float* out = (float*)d_out;
    short8* wf = (short8*)d_ws;           // 36*64*16B = 36864 B

    wfrag_kernel<<<36, 64, 0, stream>>>(w, wf);
    conv_mfma_kernel<<<B_ * 2 * 7, 384, 0, stream>>>(x, wf, out);
}